// Round 5
// baseline (258.823 us; speedup 1.0000x reference)
//
#include <hip/hip_runtime.h>
#include <cstdint>

#define TT 4096
#define BB 256
#define ID 128
#define NT 8    // tiles (64 rows each) per gates block

typedef float f32x4 __attribute__((ext_vector_type(4)));
typedef short s16x8 __attribute__((ext_vector_type(8)));

__device__ __forceinline__ float rcp_fast(float x) { return __builtin_amdgcn_rcpf(x); }
__device__ __forceinline__ float sigm(float x) { return rcp_fast(1.0f + __expf(-x)); }
__device__ __forceinline__ float tanh_fast(float x) {
  float e = __expf(2.0f * x);          // large +x -> inf -> 1; large -x -> 0 -> -1
  return 1.0f - 2.0f * rcp_fast(e + 1.0f);
}

union U16B { uint32_t u[4]; s16x8 v; };

// Split 8 f32 into bf16-hi (truncate) + bf16-lo (exact residual, truncated).
// x = hi + rest exactly up to rest's own 2^-16; 3-product GEMM error ~1e-4.
__device__ __forceinline__ void split8(const float4 a, const float4 b,
                                       s16x8& hi, s16x8& lo) {
  uint32_t a0 = __float_as_uint(a.x), a1 = __float_as_uint(a.y);
  uint32_t a2 = __float_as_uint(a.z), a3 = __float_as_uint(a.w);
  uint32_t b0 = __float_as_uint(b.x), b1 = __float_as_uint(b.y);
  uint32_t b2 = __float_as_uint(b.z), b3 = __float_as_uint(b.w);
  U16B h;
  h.u[0] = (a0 >> 16) | (a1 & 0xffff0000u);
  h.u[1] = (a2 >> 16) | (a3 & 0xffff0000u);
  h.u[2] = (b0 >> 16) | (b1 & 0xffff0000u);
  h.u[3] = (b2 >> 16) | (b3 & 0xffff0000u);
  hi = h.v;
  float r0 = a.x - __uint_as_float(a0 & 0xffff0000u);
  float r1 = a.y - __uint_as_float(a1 & 0xffff0000u);
  float r2 = a.z - __uint_as_float(a2 & 0xffff0000u);
  float r3 = a.w - __uint_as_float(a3 & 0xffff0000u);
  float r4 = b.x - __uint_as_float(b0 & 0xffff0000u);
  float r5 = b.y - __uint_as_float(b1 & 0xffff0000u);
  float r6 = b.z - __uint_as_float(b2 & 0xffff0000u);
  float r7 = b.w - __uint_as_float(b3 & 0xffff0000u);
  U16B l;
  l.u[0] = (__float_as_uint(r0) >> 16) | (__float_as_uint(r1) & 0xffff0000u);
  l.u[1] = (__float_as_uint(r2) >> 16) | (__float_as_uint(r3) & 0xffff0000u);
  l.u[2] = (__float_as_uint(r4) >> 16) | (__float_as_uint(r5) & 0xffff0000u);
  l.u[3] = (__float_as_uint(r6) >> 16) | (__float_as_uint(r7) & 0xffff0000u);
  lo = l.v;
}

// One-time prep: build the split-bf16 B fragments for the gates GEMM in FINAL
// fragment order, so the hot kernel's B-load is 16 coalesced 16B/lane reads.
// Permuted-B mapping (R3/R4-verified): output col m holds gate
//   gp = (m&3)*8 + (m>>2)   (xg layout [row][j][comp], comp = i,f,g,o)
// Also packs bo[m] = b_ih[gp]+b_hh[gp].
__global__ __launch_bounds__(64) void prep_kernel(
    const float* __restrict__ W_ih, const float* __restrict__ b_ih,
    const float* __restrict__ b_hh,
    s16x8* __restrict__ whi, s16x8* __restrict__ wlo, float* __restrict__ bo)
{
  const int lane = threadIdx.x;              // 0..63
  const int kq   = (lane >> 4) * 2;
  const float4* __restrict__ w4 = reinterpret_cast<const float4*>(W_ih);
#pragma unroll
  for (int kc = 0; kc < 4; ++kc) {
#pragma unroll
    for (int nf = 0; nf < 2; ++nf) {
      int m  = nf * 16 + (lane & 15);
      int gp = (m & 3) * 8 + (m >> 2);
      int q0 = kc * 8 + kq;
      float4 wa = w4[gp * 32 + q0];
      float4 wb = w4[gp * 32 + q0 + 1];
      s16x8 hi, lo;
      split8(wa, wb, hi, lo);
      whi[(kc * 2 + nf) * 64 + lane] = hi;
      wlo[(kc * 2 + nf) * 64 + lane] = lo;
    }
  }
  if (lane < 32) {
    int gp = (lane & 3) * 8 + (lane >> 2);
    bo[lane] = b_ih[gp] + b_hh[gp];
  }
}

// gates via MFMA, barrier-free wave-local pipeline:
//   block = 256 thr = 4 waves; each block runs NT=8 tiles of 64 rows.
//   Wave wv stages (via global_load_lds, width 16, pre-swizzled SOURCE addr;
//   LDS dest linear per m104/m173) EXACTLY the 16 rows it later consumes
//   (slots [wv*512, wv*512+512) = rows [wv*16, wv*16+16)) -> no cross-wave
//   LDS sharing -> NO barriers. Double-buffered 2x32 KB LDS; next tile's 8
//   DMA loads stay in flight across the counted s_waitcnt vmcnt(N) (T3/T4:
//   never drain to 0 mid-loop).
// LDS layout (same as verified R0/R4): slot r*32+p holds src f4 (r, p^(r&31)).
// B fragments prepacked by prep_kernel (16 coalesced dwordx4, L2-hot).
// Store (R3/R4-verified): col m contiguous per 16-lane group; permuted-B makes
// col m = [j][comp] so the rnn reads one float4 (i,f,g,o) per (b,j).
__global__ __launch_bounds__(256) void gates_kernel(
    const float* __restrict__ x,
    const s16x8* __restrict__ whi, const s16x8* __restrict__ wlo,
    const float* __restrict__ bo, float* __restrict__ xg)
{
  __shared__ float4 xt[2][64 * 32];   // 2 x 32 KB double buffer
  const int tid  = threadIdx.x;
  const int lane = tid & 63;
  const int wv   = tid >> 6;
  const int rloc = wv * 16 + (lane & 15);    // A-frag row (wave-local 16 rows)
  const int kq   = (lane >> 4) * 2;          // quad offset of this lane's k-chunk

  const float4* __restrict__ x4 = reinterpret_cast<const float4*>(x);
  const size_t tile0 = (size_t)blockIdx.x * NT;

  // B fragments first: their first use (tile 0 MFMA) makes the compiler's
  // auto-waitcnt retire them; they never interact with the counted waits.
  s16x8 Bh[4][2], Bl[4][2];
#pragma unroll
  for (int kc = 0; kc < 4; ++kc) {
#pragma unroll
    for (int nf = 0; nf < 2; ++nf) {
      Bh[kc][nf] = whi[(kc * 2 + nf) * 64 + lane];
      Bl[kc][nf] = wlo[(kc * 2 + nf) * 64 + lane];
    }
  }
  const float bo0 = bo[lane & 15];
  const float bo1 = bo[16 + (lane & 15)];

  // Stage tile into buf: 8 global_load_lds_dwordx4 per wave, slots
  // s = (wv*8+it)*64 + lane; LDS dest = uniform base + lane*16 (linear);
  // source pre-swizzled: f4 (r, (s&31)^(r&31)) with r = s>>5. The permutation
  // stays inside each 512B row -> coalesced at cache-line granularity.
#define STAGE(buf, tile) do {                                                  \
    const float4* tsrc_ = x4 + (size_t)(tile) * 2048;                          \
    _Pragma("unroll")                                                          \
    for (int it_ = 0; it_ < 8; ++it_) {                                        \
      int s_ = (wv * 8 + it_) * 64 + lane;                                     \
      int r_ = s_ >> 5;                                                        \
      int q_ = (s_ & 31) ^ (r_ & 31);                                          \
      __builtin_amdgcn_global_load_lds(                                        \
          (const __attribute__((address_space(1))) void*)(tsrc_ + r_ * 32 + q_), \
          (__attribute__((address_space(3))) void*)(&xt[(buf)][(wv * 8 + it_) * 64]), \
          16, 0, 0);                                                           \
    }                                                                          \
  } while (0)

  STAGE(0, tile0);

#pragma unroll 1
  for (int t = 0; t < NT; ++t) {
    const int cur = t & 1;
    if (t + 1 < NT) STAGE(cur ^ 1, tile0 + t + 1);

    // Per-wave vmcnt bookkeeping (oldest-first retire):
    //  t==0:    [T0(8)][T1(8)]                    -> vmcnt(8) retires T0
    //  middle:  [Tt(8)][stores(8)][Tt+1(8)]       -> vmcnt(16) retires Tt
    //  t==NT-1: [Tlast(8)][stores(8)]             -> vmcnt(8) retires Tlast
    if (t == 0 || t + 1 >= NT) {
      asm volatile("s_waitcnt vmcnt(8)" ::: "memory");
    } else {
      asm volatile("s_waitcnt vmcnt(16)" ::: "memory");
    }

    f32x4 acc[2] = {{0.f, 0.f, 0.f, 0.f}, {0.f, 0.f, 0.f, 0.f}};
#pragma unroll
    for (int kc = 0; kc < 4; ++kc) {
      int q0 = kc * 8 + kq;
      float4 xa = xt[cur][rloc * 32 + (q0 ^ (rloc & 31))];
      float4 xb = xt[cur][rloc * 32 + ((q0 + 1) ^ (rloc & 31))];
      s16x8 Ah, Al;
      split8(xa, xb, Ah, Al);
#pragma unroll
      for (int nf = 0; nf < 2; ++nf) {
        acc[nf] = __builtin_amdgcn_mfma_f32_16x16x32_bf16(Ah, Bh[kc][nf], acc[nf], 0, 0, 0);
        acc[nf] = __builtin_amdgcn_mfma_f32_16x16x32_bf16(Ah, Bl[kc][nf], acc[nf], 0, 0, 0);
        acc[nf] = __builtin_amdgcn_mfma_f32_16x16x32_bf16(Al, Bh[kc][nf], acc[nf], 0, 0, 0);
      }
    }

    // C/D: col = lane&15, row = (lane>>4)*4 + reg  [m89-verified]
    const size_t row0 = (tile0 + t) * 64;
#pragma unroll
    for (int nf = 0; nf < 2; ++nf) {
      int m = nf * 16 + (lane & 15);
      float bb = nf ? bo1 : bo0;
      size_t rowg = row0 + wv * 16 + (lane >> 4) * 4;
#pragma unroll
      for (int reg = 0; reg < 4; ++reg) {
        xg[(rowg + reg) * 32 + m] = acc[nf][reg] + bb;
      }
    }
  }
#undef STAGE
}

// rnn: 1-wave blocks, grid (33 segments, 32 batch-chunks of 8).
// Lane = (b-sub, j). Deep register prefetch: 8-step chunks, double-buffered,
// static indexing only. One coalesced float4 load per step (i,f,g,o for this
// lane's (b,j)) thanks to the permuted xg layout — wave reads 1 KiB contiguous.
__global__ __launch_bounds__(64) void rnn_kernel(
    const float* __restrict__ xg, const int* __restrict__ reset_idx,
    const float* __restrict__ W_hh, const float* __restrict__ W_proj,
    const float* __restrict__ b_proj, float* __restrict__ out)
{
  const int seg  = blockIdx.x;          // 0..32
  const int lane = threadIdx.x;
  const int j    = lane & 7;
  const int b    = blockIdx.y * 8 + (lane >> 3);

  const int start = (seg == 0)  ? 0  : reset_idx[seg - 1];
  const int end   = (seg == 32) ? TT : reset_idx[seg];
  if (start >= end) return;

  float wi[8], wf[8], wg_[8], wo[8];
#pragma unroll
  for (int k = 0; k < 8; ++k) {
    wi[k]  = W_hh[(0  + j) * 8 + k];
    wf[k]  = W_hh[(8  + j) * 8 + k];
    wg_[k] = W_hh[(16 + j) * 8 + k];
    wo[k]  = W_hh[(24 + j) * 8 + k];
  }
  const float bp = b_proj[0];
  float wp[8];
#pragma unroll
  for (int k = 0; k < 8; ++k) wp[k] = W_proj[k];

  float h[8];
#pragma unroll
  for (int k = 0; k < 8; ++k) h[k] = 0.f;
  float c = 0.f;

  float* __restrict__ vout = out;                    // value   [T*B]
  float* __restrict__ hout = out + (size_t)TT * BB;  // rnn_out [T*B*8]

  const float4* __restrict__ xg4 = reinterpret_cast<const float4*>(xg);
  const size_t lbase = (size_t)b * 8 + j;            // + t*2048

  float4 bufA[8], bufB[8];

#define LOADC(buf, tc) do {                                                  \
  _Pragma("unroll")                                                          \
  for (int s = 0; s < 8; ++s) {                                              \
    int tt = (tc) + s; tt = tt < TT ? tt : TT - 1;   /* clamp: always valid */\
    (buf)[s] = xg4[(size_t)tt * 2048 + lbase];                               \
  }                                                                          \
} while (0)

#define STEP8(buf, tc) do {                                                  \
  _Pragma("unroll")                                                          \
  for (int s = 0; s < 8; ++s) {                                              \
    int t = (tc) + s;                                                        \
    if (t < end) {       /* wave-uniform branch */                           \
      float gi = (buf)[s].x, gf = (buf)[s].y;                                \
      float gg = (buf)[s].z, go = (buf)[s].w;                                \
      float gi1 = 0.f, gf1 = 0.f, gg1 = 0.f, go1 = 0.f;                      \
      _Pragma("unroll")                                                      \
      for (int k = 0; k < 8; k += 2) {                                       \
        gi += wi[k]  * h[k];  gi1 += wi[k+1]  * h[k+1];                      \
        gf += wf[k]  * h[k];  gf1 += wf[k+1]  * h[k+1];                      \
        gg += wg_[k] * h[k];  gg1 += wg_[k+1] * h[k+1];                      \
        go += wo[k]  * h[k];  go1 += wo[k+1]  * h[k+1];                      \
      }                                                                      \
      gi += gi1; gf += gf1; gg += gg1; go += go1;                            \
      float si = sigm(gi), sf = sigm(gf), sg = tanh_fast(gg), so = sigm(go); \
      c = sf * c + si * sg;                                                  \
      float hj = so * tanh_fast(c);                                          \
      hout[((size_t)t * BB + b) * 8 + j] = hj;                               \
      _Pragma("unroll")                                                      \
      for (int k = 0; k < 8; ++k) h[k] = __shfl(hj, k, 8);                   \
      float sv = bp;                                                         \
      _Pragma("unroll")                                                      \
      for (int k = 0; k < 8; ++k) sv += wp[k] * h[k];                        \
      if (j == 0) vout[(size_t)t * BB + b] = sv;                             \
    }                                                                        \
  }                                                                          \
} while (0)

  LOADC(bufA, start);
  LOADC(bufB, start + 8);
  for (int tc = start; tc < end; tc += 16) {
    STEP8(bufA, tc);
    LOADC(bufA, tc + 16);      // ~8 steps ahead of use
    STEP8(bufB, tc + 8);
    LOADC(bufB, tc + 24);
  }
#undef LOADC
#undef STEP8
}

extern "C" void kernel_launch(void* const* d_in, const int* in_sizes, int n_in,
                              void* d_out, int out_size, void* d_ws, size_t ws_size,
                              hipStream_t stream) {
  const float* x      = (const float*)d_in[0];
  const int*   ridx   = (const int*)  d_in[1];
  const float* W_ih   = (const float*)d_in[2];
  const float* W_hh   = (const float*)d_in[3];
  const float* b_ih   = (const float*)d_in[4];
  const float* b_hh   = (const float*)d_in[5];
  const float* W_proj = (const float*)d_in[6];
  const float* b_proj = (const float*)d_in[7];
  float* out = (float*)d_out;

  float* xg  = (float*)d_ws;                          // T*B*32 f32 = 128 MiB
  char*  aux = (char*)d_ws + (size_t)134217728;       // after xg
  s16x8* whi = (s16x8*)aux;                           // 512 * 16 B = 8 KiB
  s16x8* wlo = whi + 512;                             // 8 KiB
  float* bo  = (float*)(wlo + 512);                   // 32 floats

  prep_kernel<<<1, 64, 0, stream>>>(W_ih, b_ih, b_hh, whi, wlo, bo);
  gates_kernel<<<(TT * BB) / (64 * NT), 256, 0, stream>>>(x, whi, wlo, bo, xg);
  rnn_kernel<<<dim3(33, 32), 64, 0, stream>>>(xg, ridx, W_hh, W_proj, b_proj, out);
}

// Round 6
// 256.919 us; speedup vs baseline: 1.0074x; 1.0074x over previous
//
#include <hip/hip_runtime.h>
#include <cstdint>

#define TT 4096
#define BB 256
#define ID 128

typedef float f32x4 __attribute__((ext_vector_type(4)));
typedef short s16x8 __attribute__((ext_vector_type(8)));
typedef _Float16 h16x4 __attribute__((ext_vector_type(4)));

__device__ __forceinline__ float rcp_fast(float x) { return __builtin_amdgcn_rcpf(x); }
__device__ __forceinline__ float sigm(float x) { return rcp_fast(1.0f + __expf(-x)); }
__device__ __forceinline__ float tanh_fast(float x) {
  float e = __expf(2.0f * x);          // large +x -> inf -> 1; large -x -> 0 -> -1
  return 1.0f - 2.0f * rcp_fast(e + 1.0f);
}

union U16B { uint32_t u[4]; s16x8 v; };

// Split 8 f32 into bf16-hi (truncate) + bf16-lo (exact residual, truncated).
// x = hi + rest exactly up to rest's own 2^-16; 3-product GEMM error ~1e-4.
__device__ __forceinline__ void split8(const float4 a, const float4 b,
                                       s16x8& hi, s16x8& lo) {
  uint32_t a0 = __float_as_uint(a.x), a1 = __float_as_uint(a.y);
  uint32_t a2 = __float_as_uint(a.z), a3 = __float_as_uint(a.w);
  uint32_t b0 = __float_as_uint(b.x), b1 = __float_as_uint(b.y);
  uint32_t b2 = __float_as_uint(b.z), b3 = __float_as_uint(b.w);
  U16B h;
  h.u[0] = (a0 >> 16) | (a1 & 0xffff0000u);
  h.u[1] = (a2 >> 16) | (a3 & 0xffff0000u);
  h.u[2] = (b0 >> 16) | (b1 & 0xffff0000u);
  h.u[3] = (b2 >> 16) | (b3 & 0xffff0000u);
  hi = h.v;
  float r0 = a.x - __uint_as_float(a0 & 0xffff0000u);
  float r1 = a.y - __uint_as_float(a1 & 0xffff0000u);
  float r2 = a.z - __uint_as_float(a2 & 0xffff0000u);
  float r3 = a.w - __uint_as_float(a3 & 0xffff0000u);
  float r4 = b.x - __uint_as_float(b0 & 0xffff0000u);
  float r5 = b.y - __uint_as_float(b1 & 0xffff0000u);
  float r6 = b.z - __uint_as_float(b2 & 0xffff0000u);
  float r7 = b.w - __uint_as_float(b3 & 0xffff0000u);
  U16B l;
  l.u[0] = (__float_as_uint(r0) >> 16) | (__float_as_uint(r1) & 0xffff0000u);
  l.u[1] = (__float_as_uint(r2) >> 16) | (__float_as_uint(r3) & 0xffff0000u);
  l.u[2] = (__float_as_uint(r4) >> 16) | (__float_as_uint(r5) & 0xffff0000u);
  l.u[3] = (__float_as_uint(r6) >> 16) | (__float_as_uint(r7) & 0xffff0000u);
  lo = l.v;
}

// One-time prep: split-bf16 W fragments for the gates GEMM, W used as the
// *A* operand (transposed-D trick). A-row r of frag nf holds gate
//   gA(r) = (r&3)*8 + nf*4 + (r>>2)
// so D[row=qD*4+reg][col=xrow] = comp reg (i,f,g,o) of unit u = nf*4+qD.
// Lane (c=lane&15, q=lane>>4) holds W[gA(c)][k = kc*32 + q*8 + 0..7].
// Also packs bo4[u] = float4 of (b_ih+b_hh)[{0,8,16,24}+u].
__global__ __launch_bounds__(64) void prep_kernel(
    const float* __restrict__ W_ih, const float* __restrict__ b_ih,
    const float* __restrict__ b_hh,
    s16x8* __restrict__ whi, s16x8* __restrict__ wlo, float4* __restrict__ bo4)
{
  const int lane = threadIdx.x;              // 0..63
  const int c    = lane & 15;
  const int kq   = (lane >> 4) * 2;
  const float4* __restrict__ w4 = reinterpret_cast<const float4*>(W_ih);
#pragma unroll
  for (int kc = 0; kc < 4; ++kc) {
#pragma unroll
    for (int nf = 0; nf < 2; ++nf) {
      int gA = (c & 3) * 8 + nf * 4 + (c >> 2);
      int q0 = kc * 8 + kq;
      float4 wa = w4[gA * 32 + q0];
      float4 wb = w4[gA * 32 + q0 + 1];
      s16x8 hi, lo;
      split8(wa, wb, hi, lo);
      whi[(kc * 2 + nf) * 64 + lane] = hi;
      wlo[(kc * 2 + nf) * 64 + lane] = lo;
    }
  }
  if (lane < 8) {
    float4 b;
    b.x = b_ih[lane]      + b_hh[lane];        // i
    b.y = b_ih[8 + lane]  + b_hh[8 + lane];    // f
    b.z = b_ih[16 + lane] + b_hh[16 + lane];   // g
    b.w = b_ih[24 + lane] + b_hh[24 + lane];   // o
    bo4[lane] = b;
  }
}

// gates via MFMA (transposed D): block = 64 flat rows (t,b), 256 thr = 4 waves.
// x tile staged in LDS (32 KB, f4-quad XOR swizzle, R0/R4-verified path).
// W = A operand (prepacked split-bf16 frags, L2-hot coalesced loads);
// x = B operand — per-lane fragment content identical to the old A-frag, so
// the LDS read path is byte-identical to R4. D[row=gate][col=xrow]:
// lane (c',qD) holds the 4 comps (i,f,g,o) of unit u = nf*4+qD for x-row c'
// -> one packed fp16x4 store per frag. xg is FP16: halves the xg round-trip
// HBM traffic (the BW-bound kernel's only real lever).
// xg layout: h16x4 idx = row*8 + u  (row = t*256+b, u = unit 0..7).
__global__ __launch_bounds__(256) void gates_kernel(
    const float* __restrict__ x,
    const s16x8* __restrict__ whi, const s16x8* __restrict__ wlo,
    const float4* __restrict__ bo4, _Float16* __restrict__ xg)
{
  __shared__ float4 xt[64 * 32];   // 32 KB  [row][q ^ (row&31)]
  const int tid = threadIdx.x;
  const size_t row0 = (size_t)blockIdx.x * 64;

  const float4* __restrict__ src = reinterpret_cast<const float4*>(x) + row0 * 32;
#pragma unroll
  for (int it = 0; it < 8; ++it) {           // 2048 f4, coalesced
    int idx = it * 256 + tid;
    int r = idx >> 5, q = idx & 31;
    xt[r * 32 + (q ^ (r & 31))] = src[idx];
  }

  const int lane = tid & 63;
  const int wv   = tid >> 6;
  const int rloc = wv * 16 + (lane & 15);    // x-row this lane carries (B-frag col)
  const int kq   = (lane >> 4) * 2;          // quad offset of this lane's k-chunk

  // W fragments (A operand): prepacked, fragment-ordered -> coalesced 16B/lane
  // loads, L2-hot. Issued before the barrier; overlaps x staging.
  s16x8 Wh[4][2], Wl[4][2];
#pragma unroll
  for (int kc = 0; kc < 4; ++kc) {
#pragma unroll
    for (int nf = 0; nf < 2; ++nf) {
      Wh[kc][nf] = whi[(kc * 2 + nf) * 64 + lane];
      Wl[kc][nf] = wlo[(kc * 2 + nf) * 64 + lane];
    }
  }
  const int qD = lane >> 4;
  const float4 bq0 = bo4[qD];        // units 0..3  (nf=0)
  const float4 bq1 = bo4[4 + qD];    // units 4..7  (nf=1)

  __syncthreads();

  f32x4 acc[2] = {{0.f, 0.f, 0.f, 0.f}, {0.f, 0.f, 0.f, 0.f}};
#pragma unroll
  for (int kc = 0; kc < 4; ++kc) {
    int q0 = kc * 8 + kq;
    float4 xa = xt[rloc * 32 + (q0 ^ (rloc & 31))];
    float4 xb = xt[rloc * 32 + ((q0 + 1) ^ (rloc & 31))];
    s16x8 Xh, Xl;
    split8(xa, xb, Xh, Xl);
#pragma unroll
    for (int nf = 0; nf < 2; ++nf) {
      acc[nf] = __builtin_amdgcn_mfma_f32_16x16x32_bf16(Wh[kc][nf], Xh, acc[nf], 0, 0, 0);
      acc[nf] = __builtin_amdgcn_mfma_f32_16x16x32_bf16(Wl[kc][nf], Xh, acc[nf], 0, 0, 0);
      acc[nf] = __builtin_amdgcn_mfma_f32_16x16x32_bf16(Wh[kc][nf], Xl, acc[nf], 0, 0, 0);
    }
  }

  // D: col = lane&15 = x-row, row = qD*4 + reg = (comp=reg, unit=nf*4+qD)
  // [m89 layout + gA permutation]. One fp16x4 store per frag.
  const int c_ = lane & 15;
  h16x4* __restrict__ xgh = reinterpret_cast<h16x4*>(xg);
  const size_t xrow = row0 + wv * 16 + c_;
  {
    h16x4 hv;
    hv[0] = (_Float16)(acc[0][0] + bq0.x);
    hv[1] = (_Float16)(acc[0][1] + bq0.y);
    hv[2] = (_Float16)(acc[0][2] + bq0.z);
    hv[3] = (_Float16)(acc[0][3] + bq0.w);
    xgh[xrow * 8 + qD] = hv;
  }
  {
    h16x4 hv;
    hv[0] = (_Float16)(acc[1][0] + bq1.x);
    hv[1] = (_Float16)(acc[1][1] + bq1.y);
    hv[2] = (_Float16)(acc[1][2] + bq1.z);
    hv[3] = (_Float16)(acc[1][3] + bq1.w);
    xgh[xrow * 8 + 4 + qD] = hv;
  }
}

// rnn: 1-wave blocks, grid (33 segments, 32 batch-chunks of 8).
// Lane = (b-sub, j). Deep register prefetch: 8-step chunks, double-buffered,
// static indexing only. One coalesced 8B fp16x4 load per step (i,f,g,o for
// this lane's (b,j)) — wave reads 512 B contiguous per step.
__global__ __launch_bounds__(64) void rnn_kernel(
    const _Float16* __restrict__ xg, const int* __restrict__ reset_idx,
    const float* __restrict__ W_hh, const float* __restrict__ W_proj,
    const float* __restrict__ b_proj, float* __restrict__ out)
{
  const int seg  = blockIdx.x;          // 0..32
  const int lane = threadIdx.x;
  const int j    = lane & 7;
  const int b    = blockIdx.y * 8 + (lane >> 3);

  const int start = (seg == 0)  ? 0  : reset_idx[seg - 1];
  const int end   = (seg == 32) ? TT : reset_idx[seg];
  if (start >= end) return;

  float wi[8], wf[8], wg_[8], wo[8];
#pragma unroll
  for (int k = 0; k < 8; ++k) {
    wi[k]  = W_hh[(0  + j) * 8 + k];
    wf[k]  = W_hh[(8  + j) * 8 + k];
    wg_[k] = W_hh[(16 + j) * 8 + k];
    wo[k]  = W_hh[(24 + j) * 8 + k];
  }
  const float bp = b_proj[0];
  float wp[8];
#pragma unroll
  for (int k = 0; k < 8; ++k) wp[k] = W_proj[k];

  float h[8];
#pragma unroll
  for (int k = 0; k < 8; ++k) h[k] = 0.f;
  float c = 0.f;

  float* __restrict__ vout = out;                    // value   [T*B]
  float* __restrict__ hout = out + (size_t)TT * BB;  // rnn_out [T*B*8]

  const h16x4* __restrict__ xgh4 = reinterpret_cast<const h16x4*>(xg);
  const size_t lbase = (size_t)b * 8 + j;            // + t*2048

  h16x4 bufA[8], bufB[8];

#define LOADC(buf, tc) do {                                                  \
  _Pragma("unroll")                                                          \
  for (int s = 0; s < 8; ++s) {                                              \
    int tt = (tc) + s; tt = tt < TT ? tt : TT - 1;   /* clamp: always valid */\
    (buf)[s] = xgh4[(size_t)tt * 2048 + lbase];                              \
  }                                                                          \
} while (0)

#define STEP8(buf, tc) do {                                                  \
  _Pragma("unroll")                                                          \
  for (int s = 0; s < 8; ++s) {                                              \
    int t = (tc) + s;                                                        \
    if (t < end) {       /* wave-uniform branch */                           \
      float gi = (float)(buf)[s][0], gf = (float)(buf)[s][1];                \
      float gg = (float)(buf)[s][2], go = (float)(buf)[s][3];                \
      float gi1 = 0.f, gf1 = 0.f, gg1 = 0.f, go1 = 0.f;                      \
      _Pragma("unroll")                                                      \
      for (int k = 0; k < 8; k += 2) {                                       \
        gi += wi[k]  * h[k];  gi1 += wi[k+1]  * h[k+1];                      \
        gf += wf[k]  * h[k];  gf1 += wf[k+1]  * h[k+1];                      \
        gg += wg_[k] * h[k];  gg1 += wg_[k+1] * h[k+1];                      \
        go += wo[k]  * h[k];  go1 += wo[k+1]  * h[k+1];                      \
      }                                                                      \
      gi += gi1; gf += gf1; gg += gg1; go += go1;                            \
      float si = sigm(gi), sf = sigm(gf), sg = tanh_fast(gg), so = sigm(go); \
      c = sf * c + si * sg;                                                  \
      float hj = so * tanh_fast(c);                                          \
      hout[((size_t)t * BB + b) * 8 + j] = hj;                               \
      _Pragma("unroll")                                                      \
      for (int k = 0; k < 8; ++k) h[k] = __shfl(hj, k, 8);                   \
      float sv = bp;                                                         \
      _Pragma("unroll")                                                      \
      for (int k = 0; k < 8; ++k) sv += wp[k] * h[k];                        \
      if (j == 0) vout[(size_t)t * BB + b] = sv;                             \
    }                                                                        \
  }                                                                          \
} while (0)

  LOADC(bufA, start);
  LOADC(bufB, start + 8);
  for (int tc = start; tc < end; tc += 16) {
    STEP8(bufA, tc);
    LOADC(bufA, tc + 16);      // ~8 steps ahead of use
    STEP8(bufB, tc + 8);
    LOADC(bufB, tc + 24);
  }
#undef LOADC
#undef STEP8
}

extern "C" void kernel_launch(void* const* d_in, const int* in_sizes, int n_in,
                              void* d_out, int out_size, void* d_ws, size_t ws_size,
                              hipStream_t stream) {
  const float* x      = (const float*)d_in[0];
  const int*   ridx   = (const int*)  d_in[1];
  const float* W_ih   = (const float*)d_in[2];
  const float* W_hh   = (const float*)d_in[3];
  const float* b_ih   = (const float*)d_in[4];
  const float* b_hh   = (const float*)d_in[5];
  const float* W_proj = (const float*)d_in[6];
  const float* b_proj = (const float*)d_in[7];
  float* out = (float*)d_out;

  _Float16* xg  = (_Float16*)d_ws;                    // T*B*32 fp16 = 64 MiB
  char*  aux = (char*)d_ws + (size_t)134217728;       // past xg (offset kept)
  s16x8* whi = (s16x8*)aux;                           // 512 * 16 B = 8 KiB
  s16x8* wlo = whi + 512;                             // 8 KiB
  float4* bo4 = (float4*)(wlo + 512);                 // 8 float4

  prep_kernel<<<1, 64, 0, stream>>>(W_ih, b_ih, b_hh, whi, wlo, bo4);
  gates_kernel<<<(TT * BB) / 64, 256, 0, stream>>>(x, whi, wlo, bo4, xg);
  rnn_kernel<<<dim3(33, 32), 64, 0, stream>>>(xg, ridx, W_hh, W_proj, b_proj, out);
}